// Round 7
// baseline (380.496 us; speedup 1.0000x reference)
//
#include <hip/hip_runtime.h>

typedef __bf16 bf16;
typedef __bf16 bf16x8 __attribute__((ext_vector_type(8)));
typedef __bf16 bf16x4 __attribute__((ext_vector_type(4)));
typedef float  f32x4  __attribute__((ext_vector_type(4)));

#define MFMA16 __builtin_amdgcn_mfma_f32_16x16x32_bf16

static constexpr int   BSZ   = 4;
static constexpr int   SEQL  = 2048;
static constexpr int   DM    = 1024;
static constexpr int   NHEAD = 16;
static constexpr int   DHEAD = 64;
static constexpr float NEGB  = -16384.0f;              // exp2 -> exact 0
static constexpr float SCL2  = 0.125f * 1.44269504f;   // folded into Wk at cvt

// async global->LDS, 16B per lane; LDS dest = wave-uniform base + lane*16
__device__ __forceinline__ void glds16(bf16* lds, const bf16* g) {
    __builtin_amdgcn_global_load_lds(
        (const __attribute__((address_space(1))) unsigned int*)g,
        (__attribute__((address_space(3))) unsigned int*)lds, 16, 0, 0);
}

// ---------------------------------------------------------------------------
// Mask dtype detection: flag 0=int32{0,1}, 1=byte, 2=float32, 3=bf16
__global__ void detect_mask(const unsigned int* __restrict__ m, int* __restrict__ flag) {
    __shared__ int ok[4];
    if (threadIdx.x < 4) ok[threadIdx.x] = 1;
    __syncthreads();
    for (int i = 0; i < 16; ++i) {
        unsigned int w = m[threadIdx.x * 16 + i];
        if (!(w == 0u || w == 1u)) ok[0] = 0;
        if (w & 0xFEFEFEFEu) ok[1] = 0;
        if (!(w == 0u || w == 0x3F800000u)) ok[2] = 0;
        unsigned lo = w & 0xFFFFu, hi = w >> 16;
        if (!((lo == 0u || lo == 0x3F80u) && (hi == 0u || hi == 0x3F80u))) ok[3] = 0;
    }
    __syncthreads();
    if (threadIdx.x == 0)
        *flag = ok[0] ? 0 : (ok[1] ? 1 : (ok[2] ? 2 : 3));
}

__device__ __forceinline__ bool mask_at(const void* m, int fl, long idx) {
    if (fl == 0) return ((const int*)m)[idx] != 0;
    if (fl == 1) return ((const unsigned char*)m)[idx] != 0;
    if (fl == 2) return ((const float*)m)[idx] != 0.0f;
    return ((const unsigned short*)m)[idx] != 0;
}

// mask -> bit matrix: word[row][kt] bit k = mask[row][kt*64+k]. One ballot/wave.
__global__ __launch_bounds__(256) void prep_bits(const void* __restrict__ mask,
                                                 const int* __restrict__ flagp,
                                                 unsigned long long* __restrict__ mb) {
    const int fl = *flagp;
    const int word = blockIdx.x * 4 + (threadIdx.x >> 6);
    const long base = (long)word * 64 + (threadIdx.x & 63);
    unsigned long long b = __ballot(mask_at(mask, fl, base));
    if ((threadIdx.x & 63) == 0) mb[word] = b;
}

// ---------------------------------------------------------------------------
// LayerNorm: one block per row of 1024. fp32 compute, bf16 out.
__global__ __launch_bounds__(256) void ln_kernel(
    const float* __restrict__ x, const float* __restrict__ g,
    const float* __restrict__ bta, bf16* __restrict__ y)
{
    const int row = blockIdx.x, t = threadIdx.x;
    const float4 v = ((const float4*)(x + (size_t)row * DM))[t];
    float s  = v.x + v.y + v.z + v.w;
    float ss = v.x * v.x + v.y * v.y + v.z * v.z + v.w * v.w;
    for (int m = 32; m >= 1; m >>= 1) { s += __shfl_xor(s, m); ss += __shfl_xor(ss, m); }
    __shared__ float red[8];
    const int w = t >> 6, L = t & 63;
    if (L == 0) { red[w] = s; red[4 + w] = ss; }
    __syncthreads();
    s  = red[0] + red[1] + red[2] + red[3];
    ss = red[4] + red[5] + red[6] + red[7];
    const float mu = s * (1.0f / DM);
    const float var = ss * (1.0f / DM) - mu * mu;
    const float r = rsqrtf(var + 1e-5f);
    const float4 gv = ((const float4*)g)[t];
    const float4 bv = ((const float4*)bta)[t];
    bf16x4 o;
    o[0] = (bf16)((v.x - mu) * r * gv.x + bv.x);
    o[1] = (bf16)((v.y - mu) * r * gv.y + bv.y);
    o[2] = (bf16)((v.z - mu) * r * gv.z + bv.z);
    o[3] = (bf16)((v.w - mu) * r * gv.w + bv.w);
    ((bf16x4*)(y + (size_t)row * DM))[t] = o;
}

// ---------------------------------------------------------------------------
// Transpose+convert 4 weight matrices (1024x1024 f32, KxN) into bf16 NxK.
// Wk (z==1) is pre-scaled by SCALE*log2e so flash scores are in log2 domain.
__global__ void cvt_w(const float* __restrict__ Wq, const float* __restrict__ Wk,
                      const float* __restrict__ Wv, const float* __restrict__ Wo,
                      bf16* __restrict__ Wt)
{
    __shared__ float tile[32][33];
    const int z = blockIdx.z;
    const float* src = (z == 0) ? Wq : (z == 1) ? Wk : (z == 2) ? Wv : Wo;
    const float scl = (z == 1) ? SCL2 : 1.0f;
    bf16* dst = Wt + (size_t)z * DM * DM;
    const int tx = threadIdx.x, ty = threadIdx.y;
    const int nIn = blockIdx.x * 32 + tx;
    const int kIn = blockIdx.y * 32;
    for (int i = 0; i < 32; i += 8)
        tile[ty + i][tx] = src[(size_t)(kIn + ty + i) * DM + nIn];
    __syncthreads();
    const int nOut = blockIdx.x * 32;
    const int kOut = blockIdx.y * 32 + tx;
    for (int i = 0; i < 32; i += 8)
        dst[(size_t)(nOut + ty + i) * DM + kOut] = (bf16)(tile[tx][ty + i] * scl);
}

// ---------------------------------------------------------------------------
// m97-style 128x128 GEMM core: A (MxK rm), Bt (NxK rm), BK=32, global_load_lds.
__device__ __forceinline__ void gemm128_core(
    const bf16* __restrict__ A, const bf16* __restrict__ Bt,
    int m0, int n0, bool swapped, f32x4 acc[4][4], bf16* Asm, bf16* Bsm)
{
    const int t = threadIdx.x, w = t >> 6, L = t & 63;
    const int lr = L & 15, lq = L >> 4;
    const int wm = w & 1, wn = w >> 1;
    const int srow = L >> 2, scol = (L & 3) * 8;
    const bf16* Ab = A  + (size_t)(m0 + w * 32 + srow) * DM + scol;
    const bf16* Bb = Bt + (size_t)(n0 + w * 32 + srow) * DM + scol;
    bf16* AsmW = Asm + (w * 32) * 32;
    bf16* BsmW = Bsm + (w * 32) * 32;
    for (int kk = 0; kk < DM; kk += 32) {
        __syncthreads();
        glds16(AsmW,           Ab + kk);
        glds16(AsmW + 16 * 32, Ab + (size_t)16 * DM + kk);
        glds16(BsmW,           Bb + kk);
        glds16(BsmW + 16 * 32, Bb + (size_t)16 * DM + kk);
        __syncthreads();
        bf16x8 af[4], bf_[4];
        #pragma unroll
        for (int i = 0; i < 4; ++i)
            af[i] = *(const bf16x8*)(Asm + (wm * 64 + i * 16 + lr) * 32 + lq * 8);
        #pragma unroll
        for (int j = 0; j < 4; ++j)
            bf_[j] = *(const bf16x8*)(Bsm + (wn * 64 + j * 16 + lr) * 32 + lq * 8);
        if (!swapped) {
            #pragma unroll
            for (int i = 0; i < 4; ++i)
                #pragma unroll
                for (int j = 0; j < 4; ++j)
                    acc[i][j] = MFMA16(af[i], bf_[j], acc[i][j], 0, 0, 0);
        } else {
            #pragma unroll
            for (int i = 0; i < 4; ++i)
                #pragma unroll
                for (int j = 0; j < 4; ++j)
                    acc[i][j] = MFMA16(bf_[j], af[i], acc[i][j], 0, 0, 0);
        }
    }
}

// Fused QKV projection, one dispatch: y -> (z = y>>3, n0 = (y&7)*128).
// z=0,1 -> Q,K in (b,h,s,d); z=2 -> V^T in (b,h,d,s).
__global__ __launch_bounds__(256) void qkv128(
    const bf16* __restrict__ qn, const bf16* __restrict__ Wt,
    bf16* __restrict__ Qb, bf16* __restrict__ Kb, bf16* __restrict__ Vtb)
{
    __shared__ __align__(16) bf16 Asm[128 * 32];
    __shared__ __align__(16) bf16 Bsm[128 * 32];
    const int ny = blockIdx.y;
    const int z = ny >> 3;
    const int m0 = blockIdx.x * 128, n0 = (ny & 7) * 128;
    f32x4 acc[4][4] = {};
    gemm128_core(qn, Wt + (size_t)z * DM * DM, m0, n0, z == 2, acc, Asm, Bsm);
    const int t = threadIdx.x, L = t & 63, w = t >> 6;
    const int wm = w & 1, wn = w >> 1, lr = L & 15, lq = L >> 4;
    if (z < 2) {
        bf16* dst = z ? Kb : Qb;
        #pragma unroll
        for (int i = 0; i < 4; ++i)
            #pragma unroll
            for (int j = 0; j < 4; ++j)
                #pragma unroll
                for (int r = 0; r < 4; ++r) {
                    int m = m0 + wm * 64 + i * 16 + lq * 4 + r;   // b*2048+s
                    int n = n0 + wn * 64 + j * 16 + lr;           // h*64+d
                    int b = m >> 11, s = m & 2047, h = n >> 6, d = n & 63;
                    dst[(((size_t)b * NHEAD + h) * SEQL + s) * DHEAD + d] = (bf16)acc[i][j][r];
                }
    } else {
        #pragma unroll
        for (int i = 0; i < 4; ++i)
            #pragma unroll
            for (int j = 0; j < 4; ++j)
                #pragma unroll
                for (int r = 0; r < 4; ++r) {
                    int dg = n0 + wn * 64 + j * 16 + lq * 4 + r;  // h*64+d (D rows)
                    int sg = m0 + wm * 64 + i * 16 + lr;          // b*2048+s (D cols)
                    int h = dg >> 6, d = dg & 63, b = sg >> 11, s = sg & 2047;
                    Vtb[(((size_t)b * NHEAD + h) * DHEAD + d) * SEQL + s] = (bf16)acc[i][j][r];
                }
    }
}

// Output projection + residual (fp32 out).
__global__ __launch_bounds__(256) void out128(
    const bf16* __restrict__ vec, const bf16* __restrict__ Wot,
    const bf16* __restrict__ qnb, float* __restrict__ out)
{
    __shared__ __align__(16) bf16 Asm[128 * 32];
    __shared__ __align__(16) bf16 Bsm[128 * 32];
    const int m0 = blockIdx.x * 128, n0 = blockIdx.y * 128;
    f32x4 acc[4][4] = {};
    gemm128_core(vec, Wot, m0, n0, false, acc, Asm, Bsm);
    const int t = threadIdx.x, L = t & 63, w = t >> 6;
    const int wm = w & 1, wn = w >> 1, lr = L & 15, lq = L >> 4;
    #pragma unroll
    for (int i = 0; i < 4; ++i)
        #pragma unroll
        for (int j = 0; j < 4; ++j)
            #pragma unroll
            for (int r = 0; r < 4; ++r) {
                int m = m0 + wm * 64 + i * 16 + lq * 4 + r;
                int n = n0 + wn * 64 + j * 16 + lr;
                size_t idx = (size_t)m * DM + n;
                out[idx] = acc[i][j][r] + (float)qnb[idx];
            }
}

// ---------------------------------------------------------------------------
// Flash attention v6: R6 structure + XCD-aware swizzle (all 16 q-blocks of a
// bh share one XCD slot -> K/V L2-resident), __launch_bounds__(256,4) VGPR
// budget, and fused select->exp2->pack (no p[][] intermediate).
// 1D grid 1024; 4 waves; wave = 32 q-rows (2 groups of 16); KV tile 64.
__global__ __launch_bounds__(256, 4) void flash_attn(
    const bf16* __restrict__ Qb, const bf16* __restrict__ Kb,
    const bf16* __restrict__ Vtb, const unsigned long long* __restrict__ mb,
    bf16* __restrict__ vec)
{
    __shared__ __align__(16) bf16 Ksm [64 * 72];     // [slot(key)][d]
    __shared__ __align__(16) bf16 Vtsm[64 * 72];     // [d][key] natural order

    const int t = threadIdx.x, w = t >> 6, L = t & 63;
    const int lr = L & 15, lq = L >> 4;
    // XCD swizzle: slot = bid&7 fixed per bh -> K/V stay in one XCD's L2
    const int bid = blockIdx.x;
    const int slot = bid & 7, rest = bid >> 3;
    const int qblk = rest & 15;
    const int bh = ((rest >> 4) << 3) + slot;
    const int b = bh >> 4, h = bh & 15;
    const int q0 = qblk * 128 + w * 32;

    const bf16* Qh  = Qb  + (size_t)bh * SEQL * DHEAD;
    const bf16* Kh  = Kb  + (size_t)bh * SEQL * DHEAD;
    const bf16* Vth = Vtb + (size_t)bh * DHEAD * SEQL;

    // Q fragments: B-layout [n=qrow][k=d], resident. [qg][ks]
    bf16x8 qf[2][2];
    #pragma unroll
    for (int qg = 0; qg < 2; ++qg)
        #pragma unroll
        for (int ks = 0; ks < 2; ++ks)
            qf[qg][ks] = *(const bf16x8*)(Qh + (size_t)(q0 + qg * 16 + lr) * DHEAD + ks * 32 + lq * 8);

    // per-lane mask row pointers (row fixed for whole kernel)
    const unsigned long long* mrow0 = mb + (size_t)(q0 + lr) * (SEQL / 64);
    const unsigned long long* mrow1 = mb + (size_t)(q0 + 16 + lr) * (SEQL / 64);

    f32x4 o[4][2] = {};                      // O^T acc: [dgroup][qg]
    f32x4 lacc[2] = {};                      // row-sum acc via ones-MFMA

    const bf16 one = (bf16)1.0f;
    const bf16x8 ones8 = {one, one, one, one, one, one, one, one};

    // staging: lane sr reads K row sr / Vt row sr; K goes to permuted slot row
    const int sr = t >> 2, sc = (t & 3) * 16;
    const int zrow = ((sr >> 2) & 1) * 32 + ((sr >> 5) & 1) * 16 + ((sr >> 3) & 3) * 4 + (sr & 3);
    bf16x8 kreg[2], vreg[2];
    kreg[0] = *(const bf16x8*)(Kh  + (size_t)sr * DHEAD + sc);
    kreg[1] = *(const bf16x8*)(Kh  + (size_t)sr * DHEAD + sc + 8);
    vreg[0] = *(const bf16x8*)(Vth + (size_t)sr * SEQL + sc);
    vreg[1] = *(const bf16x8*)(Vth + (size_t)sr * SEQL + sc + 8);

    for (int kt = 0; kt < SEQL / 64; ++kt) {
        if (kt > 0) __syncthreads();         // readers of prev tile done
        *(bf16x8*)(Ksm  + zrow * 72 + sc)     = kreg[0];
        *(bf16x8*)(Ksm  + zrow * 72 + sc + 8) = kreg[1];
        *(bf16x8*)(Vtsm + sr * 72 + sc)       = vreg[0];
        *(bf16x8*)(Vtsm + sr * 72 + sc + 8)   = vreg[1];
        if (kt < SEQL / 64 - 1) {            // prefetch next tile into regs
            const int kb2 = (kt + 1) * 64;
            kreg[0] = *(const bf16x8*)(Kh  + (size_t)(kb2 + sr) * DHEAD + sc);
            kreg[1] = *(const bf16x8*)(Kh  + (size_t)(kb2 + sr) * DHEAD + sc + 8);
            vreg[0] = *(const bf16x8*)(Vth + (size_t)sr * SEQL + kb2 + sc);
            vreg[1] = *(const bf16x8*)(Vth + (size_t)sr * SEQL + kb2 + sc + 8);
        }
        __syncthreads();

        // ---- S^T = K·Q^T (K pre-scaled; rows permuted so C-layout = B-frag)
        f32x4 s[4][2] = {};
        #pragma unroll
        for (int ks = 0; ks < 2; ++ks) {
            bf16x8 kf[4];
            #pragma unroll
            for (int jj = 0; jj < 4; ++jj)
                kf[jj] = *(const bf16x8*)(Ksm + (jj * 16 + lr) * 72 + ks * 32 + lq * 8);
            #pragma unroll
            for (int jj = 0; jj < 4; ++jj)
                #pragma unroll
                for (int qg = 0; qg < 2; ++qg)
                    s[jj][qg] = MFMA16(kf[jj], qf[qg][ks], s[jj][qg], 0, 0, 0);
        }

        // ---- fused select->exp2->pack: s -> pf directly (no p[][] array).
        // s[jj][qg][r] holds key = (jj&1)*32 + lq*8 + (jj>>1)*4 + r.
        bf16x8 pf[2][2];
        #pragma unroll
        for (int qg = 0; qg < 2; ++qg) {
            const unsigned long long wmk = (qg == 0 ? mrow0 : mrow1)[kt];
            const unsigned lo = (unsigned)(wmk >> (lq * 8));
            const unsigned hi = (unsigned)(wmk >> 32) >> (lq * 8);
            #pragma unroll
            for (int ks = 0; ks < 2; ++ks) {
                const unsigned na = (ks == 0 ? lo : hi) & 15u;          // jj = ks
                const unsigned nb = ((ks == 0 ? lo : hi) >> 4) & 15u;   // jj = 2+ks
                bf16x8 pv;
                #pragma unroll
                for (int r = 0; r < 4; ++r) {
                    pv[r]     = (bf16)exp2f(((na >> r) & 1u) ? NEGB : s[ks][qg][r]);
                    pv[4 + r] = (bf16)exp2f(((nb >> r) & 1u) ? NEGB : s[2 + ks][qg][r]);
                }
                pf[qg][ks] = pv;
            }
        }

        // ---- l += 1·P  and  O^T += V^T·P  (no barrier: P is in registers)
        #pragma unroll
        for (int ks = 0; ks < 2; ++ks) {
            #pragma unroll
            for (int qg = 0; qg < 2; ++qg)
                lacc[qg] = MFMA16(ones8, pf[qg][ks], lacc[qg], 0, 0, 0);
            #pragma unroll
            for (int dg = 0; dg < 4; ++dg) {
                bf16x8 vf = *(const bf16x8*)(Vtsm + (dg * 16 + lr) * 72 + ks * 32 + lq * 8);
                #pragma unroll
                for (int qg = 0; qg < 2; ++qg)
                    o[dg][qg] = MFMA16(vf, pf[qg][ks], o[dg][qg], 0, 0, 0);
            }
        }
    }

    // ---- epilogue: vec[b][s][h*64+d]; lane qrow=lr, d=dg*16+lq*4+r -> b64 stores
    #pragma unroll
    for (int qg = 0; qg < 2; ++qg) {
        const float rl = 1.0f / lacc[qg][0];
        const size_t rowb = ((size_t)b * SEQL + q0 + qg * 16 + lr) * DM + h * DHEAD;
        #pragma unroll
        for (int dg = 0; dg < 4; ++dg) {
            bf16x4 ov;
            #pragma unroll
            for (int r = 0; r < 4; ++r) ov[r] = (bf16)(o[dg][qg][r] * rl);
            *(bf16x4*)(vec + rowb + dg * 16 + lq * 4) = ov;
        }
    }
}

// ---------------------------------------------------------------------------
extern "C" void kernel_launch(void* const* d_in, const int* in_sizes, int n_in,
                              void* d_out, int out_size, void* d_ws, size_t ws_size,
                              hipStream_t stream)
{
    const float* qin   = (const float*)d_in[0];
    const void*  mask  = d_in[1];
    const float* Wq    = (const float*)d_in[2];
    const float* Wk    = (const float*)d_in[3];
    const float* Wv    = (const float*)d_in[4];
    const float* Wo    = (const float*)d_in[5];
    const float* gamma = (const float*)d_in[6];
    const float* beta  = (const float*)d_in[7];
    float* out = (float*)d_out;

    char* w = (char*)d_ws;
    int*  flag = (int*)w;
    bf16* qnb  = (bf16*)(w + 256);                 // 8192x1024 bf16  (16 MB)
    bf16* Wt   = qnb + (size_t)8192 * 1024;        // 4x 1024x1024 bf16 (8 MB)
    bf16* Qb   = Wt + (size_t)4 * 1024 * 1024;     // (b,h,s,d)  (16 MB)
    bf16* Kb   = Qb + (size_t)8192 * 1024;         // (b,h,s,d)  (16 MB)
    bf16* Vtb  = Kb + (size_t)8192 * 1024;         // (b,h,d,s)  (16 MB)
    bf16* vec  = Vtb + (size_t)8192 * 1024;        // (b,s,h*d)  (16 MB)
    unsigned long long* mb = (unsigned long long*)(vec + (size_t)8192 * 1024); // 512 KB

    detect_mask<<<1, 256, 0, stream>>>((const unsigned int*)mask, flag);
    prep_bits<<<SEQL * (SEQL / 64) / 4, 256, 0, stream>>>(mask, flag, mb);
    ln_kernel<<<8192, 256, 0, stream>>>(qin, gamma, beta, qnb);
    cvt_w<<<dim3(32, 32, 4), dim3(32, 8), 0, stream>>>(Wq, Wk, Wv, Wo, Wt);
    qkv128<<<dim3(64, 24), 256, 0, stream>>>(qnb, Wt, Qb, Kb, Vtb);
    flash_attn<<<1024, 256, 0, stream>>>(Qb, Kb, Vtb, mb, vec);
    out128<<<dim3(64, 8), 256, 0, stream>>>(vec, Wt + (size_t)3 * 1024 * 1024, qnb, out);
}

// Round 8
// 358.400 us; speedup vs baseline: 1.0617x; 1.0617x over previous
//
#include <hip/hip_runtime.h>

typedef __bf16 bf16;
typedef __bf16 bf16x8 __attribute__((ext_vector_type(8)));
typedef __bf16 bf16x4 __attribute__((ext_vector_type(4)));
typedef float  f32x4  __attribute__((ext_vector_type(4)));

#define MFMA16 __builtin_amdgcn_mfma_f32_16x16x32_bf16

static constexpr int   BSZ   = 4;
static constexpr int   SEQL  = 2048;
static constexpr int   DM    = 1024;
static constexpr int   NHEAD = 16;
static constexpr int   DHEAD = 64;
static constexpr float NEGB  = -16384.0f;              // exp2 -> exact 0
static constexpr float SCL2  = 0.125f * 1.44269504f;   // folded into Wk at cvt

// async global->LDS, 16B per lane; LDS dest = wave-uniform base + lane*16
__device__ __forceinline__ void glds16(bf16* lds, const bf16* g) {
    __builtin_amdgcn_global_load_lds(
        (const __attribute__((address_space(1))) unsigned int*)g,
        (__attribute__((address_space(3))) unsigned int*)lds, 16, 0, 0);
}

// ---------------------------------------------------------------------------
// Mask dtype detection: flag 0=int32{0,1}, 1=byte, 2=float32, 3=bf16
__global__ void detect_mask(const unsigned int* __restrict__ m, int* __restrict__ flag) {
    __shared__ int ok[4];
    if (threadIdx.x < 4) ok[threadIdx.x] = 1;
    __syncthreads();
    for (int i = 0; i < 16; ++i) {
        unsigned int w = m[threadIdx.x * 16 + i];
        if (!(w == 0u || w == 1u)) ok[0] = 0;
        if (w & 0xFEFEFEFEu) ok[1] = 0;
        if (!(w == 0u || w == 0x3F800000u)) ok[2] = 0;
        unsigned lo = w & 0xFFFFu, hi = w >> 16;
        if (!((lo == 0u || lo == 0x3F80u) && (hi == 0u || hi == 0x3F80u))) ok[3] = 0;
    }
    __syncthreads();
    if (threadIdx.x == 0)
        *flag = ok[0] ? 0 : (ok[1] ? 1 : (ok[2] ? 2 : 3));
}

__device__ __forceinline__ bool mask_at(const void* m, int fl, long idx) {
    if (fl == 0) return ((const int*)m)[idx] != 0;
    if (fl == 1) return ((const unsigned char*)m)[idx] != 0;
    if (fl == 2) return ((const float*)m)[idx] != 0.0f;
    return ((const unsigned short*)m)[idx] != 0;
}

// mask -> bit matrix: word[row][kt] bit k = mask[row][kt*64+k]. One ballot/wave.
__global__ __launch_bounds__(256) void prep_bits(const void* __restrict__ mask,
                                                 const int* __restrict__ flagp,
                                                 unsigned long long* __restrict__ mb) {
    const int fl = *flagp;
    const int word = blockIdx.x * 4 + (threadIdx.x >> 6);
    const long base = (long)word * 64 + (threadIdx.x & 63);
    unsigned long long b = __ballot(mask_at(mask, fl, base));
    if ((threadIdx.x & 63) == 0) mb[word] = b;
}

// ---------------------------------------------------------------------------
// LayerNorm: one block per row of 1024. fp32 compute, bf16 out.
__global__ __launch_bounds__(256) void ln_kernel(
    const float* __restrict__ x, const float* __restrict__ g,
    const float* __restrict__ bta, bf16* __restrict__ y)
{
    const int row = blockIdx.x, t = threadIdx.x;
    const float4 v = ((const float4*)(x + (size_t)row * DM))[t];
    float s  = v.x + v.y + v.z + v.w;
    float ss = v.x * v.x + v.y * v.y + v.z * v.z + v.w * v.w;
    for (int m = 32; m >= 1; m >>= 1) { s += __shfl_xor(s, m); ss += __shfl_xor(ss, m); }
    __shared__ float red[8];
    const int w = t >> 6, L = t & 63;
    if (L == 0) { red[w] = s; red[4 + w] = ss; }
    __syncthreads();
    s  = red[0] + red[1] + red[2] + red[3];
    ss = red[4] + red[5] + red[6] + red[7];
    const float mu = s * (1.0f / DM);
    const float var = ss * (1.0f / DM) - mu * mu;
    const float r = rsqrtf(var + 1e-5f);
    const float4 gv = ((const float4*)g)[t];
    const float4 bv = ((const float4*)bta)[t];
    bf16x4 o;
    o[0] = (bf16)((v.x - mu) * r * gv.x + bv.x);
    o[1] = (bf16)((v.y - mu) * r * gv.y + bv.y);
    o[2] = (bf16)((v.z - mu) * r * gv.z + bv.z);
    o[3] = (bf16)((v.w - mu) * r * gv.w + bv.w);
    ((bf16x4*)(y + (size_t)row * DM))[t] = o;
}

// ---------------------------------------------------------------------------
// Transpose+convert 4 weight matrices (1024x1024 f32, KxN) into bf16 NxK.
// Wk (z==1) is pre-scaled by SCALE*log2e so flash scores are in log2 domain.
__global__ void cvt_w(const float* __restrict__ Wq, const float* __restrict__ Wk,
                      const float* __restrict__ Wv, const float* __restrict__ Wo,
                      bf16* __restrict__ Wt)
{
    __shared__ float tile[32][33];
    const int z = blockIdx.z;
    const float* src = (z == 0) ? Wq : (z == 1) ? Wk : (z == 2) ? Wv : Wo;
    const float scl = (z == 1) ? SCL2 : 1.0f;
    bf16* dst = Wt + (size_t)z * DM * DM;
    const int tx = threadIdx.x, ty = threadIdx.y;
    const int nIn = blockIdx.x * 32 + tx;
    const int kIn = blockIdx.y * 32;
    for (int i = 0; i < 32; i += 8)
        tile[ty + i][tx] = src[(size_t)(kIn + ty + i) * DM + nIn];
    __syncthreads();
    const int nOut = blockIdx.x * 32;
    const int kOut = blockIdx.y * 32 + tx;
    for (int i = 0; i < 32; i += 8)
        dst[(size_t)(nOut + ty + i) * DM + kOut] = (bf16)(tile[tx][ty + i] * scl);
}

// ---------------------------------------------------------------------------
// m97-style 128x128 GEMM core: A (MxK rm), Bt (NxK rm), BK=32, global_load_lds.
__device__ __forceinline__ void gemm128_core(
    const bf16* __restrict__ A, const bf16* __restrict__ Bt,
    int m0, int n0, bool swapped, f32x4 acc[4][4], bf16* Asm, bf16* Bsm)
{
    const int t = threadIdx.x, w = t >> 6, L = t & 63;
    const int lr = L & 15, lq = L >> 4;
    const int wm = w & 1, wn = w >> 1;
    const int srow = L >> 2, scol = (L & 3) * 8;
    const bf16* Ab = A  + (size_t)(m0 + w * 32 + srow) * DM + scol;
    const bf16* Bb = Bt + (size_t)(n0 + w * 32 + srow) * DM + scol;
    bf16* AsmW = Asm + (w * 32) * 32;
    bf16* BsmW = Bsm + (w * 32) * 32;
    for (int kk = 0; kk < DM; kk += 32) {
        __syncthreads();
        glds16(AsmW,           Ab + kk);
        glds16(AsmW + 16 * 32, Ab + (size_t)16 * DM + kk);
        glds16(BsmW,           Bb + kk);
        glds16(BsmW + 16 * 32, Bb + (size_t)16 * DM + kk);
        __syncthreads();
        bf16x8 af[4], bf_[4];
        #pragma unroll
        for (int i = 0; i < 4; ++i)
            af[i] = *(const bf16x8*)(Asm + (wm * 64 + i * 16 + lr) * 32 + lq * 8);
        #pragma unroll
        for (int j = 0; j < 4; ++j)
            bf_[j] = *(const bf16x8*)(Bsm + (wn * 64 + j * 16 + lr) * 32 + lq * 8);
        if (!swapped) {
            #pragma unroll
            for (int i = 0; i < 4; ++i)
                #pragma unroll
                for (int j = 0; j < 4; ++j)
                    acc[i][j] = MFMA16(af[i], bf_[j], acc[i][j], 0, 0, 0);
        } else {
            #pragma unroll
            for (int i = 0; i < 4; ++i)
                #pragma unroll
                for (int j = 0; j < 4; ++j)
                    acc[i][j] = MFMA16(bf_[j], af[i], acc[i][j], 0, 0, 0);
        }
    }
}

// Fused QKV projection, one dispatch: y -> (z = y>>3, n0 = (y&7)*128).
// z=0,1 -> Q,K in (b,h,s,d); z=2 -> V^T in (b,h,d,s).
__global__ __launch_bounds__(256) void qkv128(
    const bf16* __restrict__ qn, const bf16* __restrict__ Wt,
    bf16* __restrict__ Qb, bf16* __restrict__ Kb, bf16* __restrict__ Vtb)
{
    __shared__ __align__(16) bf16 Asm[128 * 32];
    __shared__ __align__(16) bf16 Bsm[128 * 32];
    const int ny = blockIdx.y;
    const int z = ny >> 3;
    const int m0 = blockIdx.x * 128, n0 = (ny & 7) * 128;
    f32x4 acc[4][4] = {};
    gemm128_core(qn, Wt + (size_t)z * DM * DM, m0, n0, z == 2, acc, Asm, Bsm);
    const int t = threadIdx.x, L = t & 63, w = t >> 6;
    const int wm = w & 1, wn = w >> 1, lr = L & 15, lq = L >> 4;
    if (z < 2) {
        bf16* dst = z ? Kb : Qb;
        #pragma unroll
        for (int i = 0; i < 4; ++i)
            #pragma unroll
            for (int j = 0; j < 4; ++j)
                #pragma unroll
                for (int r = 0; r < 4; ++r) {
                    int m = m0 + wm * 64 + i * 16 + lq * 4 + r;   // b*2048+s
                    int n = n0 + wn * 64 + j * 16 + lr;           // h*64+d
                    int b = m >> 11, s = m & 2047, h = n >> 6, d = n & 63;
                    dst[(((size_t)b * NHEAD + h) * SEQL + s) * DHEAD + d] = (bf16)acc[i][j][r];
                }
    } else {
        #pragma unroll
        for (int i = 0; i < 4; ++i)
            #pragma unroll
            for (int j = 0; j < 4; ++j)
                #pragma unroll
                for (int r = 0; r < 4; ++r) {
                    int dg = n0 + wn * 64 + j * 16 + lq * 4 + r;  // h*64+d (D rows)
                    int sg = m0 + wm * 64 + i * 16 + lr;          // b*2048+s (D cols)
                    int h = dg >> 6, d = dg & 63, b = sg >> 11, s = sg & 2047;
                    Vtb[(((size_t)b * NHEAD + h) * DHEAD + d) * SEQL + s] = (bf16)acc[i][j][r];
                }
    }
}

// Output projection + residual (fp32 out).
__global__ __launch_bounds__(256) void out128(
    const bf16* __restrict__ vec, const bf16* __restrict__ Wot,
    const bf16* __restrict__ qnb, float* __restrict__ out)
{
    __shared__ __align__(16) bf16 Asm[128 * 32];
    __shared__ __align__(16) bf16 Bsm[128 * 32];
    const int m0 = blockIdx.x * 128, n0 = blockIdx.y * 128;
    f32x4 acc[4][4] = {};
    gemm128_core(vec, Wot, m0, n0, false, acc, Asm, Bsm);
    const int t = threadIdx.x, L = t & 63, w = t >> 6;
    const int wm = w & 1, wn = w >> 1, lr = L & 15, lq = L >> 4;
    #pragma unroll
    for (int i = 0; i < 4; ++i)
        #pragma unroll
        for (int j = 0; j < 4; ++j)
            #pragma unroll
            for (int r = 0; r < 4; ++r) {
                int m = m0 + wm * 64 + i * 16 + lq * 4 + r;
                int n = n0 + wn * 64 + j * 16 + lr;
                size_t idx = (size_t)m * DM + n;
                out[idx] = acc[i][j][r] + (float)qnb[idx];
            }
}

// ---------------------------------------------------------------------------
// Flash attention v7: R6 register structure (plain launch bounds -> ~92 VGPR,
// no scratch spills) + R7's XCD swizzle (K/V L2-resident, FETCH 33 MB) and
// fused select->exp2->pack. 1D grid 1024; 4 waves; wave = 32 q-rows.
__global__ __launch_bounds__(256) void flash_attn(
    const bf16* __restrict__ Qb, const bf16* __restrict__ Kb,
    const bf16* __restrict__ Vtb, const unsigned long long* __restrict__ mb,
    bf16* __restrict__ vec)
{
    __shared__ __align__(16) bf16 Ksm [64 * 72];     // [slot(key)][d]
    __shared__ __align__(16) bf16 Vtsm[64 * 72];     // [d][key] natural order

    const int t = threadIdx.x, w = t >> 6, L = t & 63;
    const int lr = L & 15, lq = L >> 4;
    // XCD swizzle: slot = bid&7 fixed per bh -> K/V stay in one XCD's L2
    const int bid = blockIdx.x;
    const int slot = bid & 7, rest = bid >> 3;
    const int qblk = rest & 15;
    const int bh = ((rest >> 4) << 3) + slot;
    const int b = bh >> 4, h = bh & 15;
    const int q0 = qblk * 128 + w * 32;

    const bf16* Qh  = Qb  + (size_t)bh * SEQL * DHEAD;
    const bf16* Kh  = Kb  + (size_t)bh * SEQL * DHEAD;
    const bf16* Vth = Vtb + (size_t)bh * DHEAD * SEQL;

    // Q fragments: B-layout [n=qrow][k=d], resident. [qg][ks]
    bf16x8 qf[2][2];
    #pragma unroll
    for (int qg = 0; qg < 2; ++qg)
        #pragma unroll
        for (int ks = 0; ks < 2; ++ks)
            qf[qg][ks] = *(const bf16x8*)(Qh + (size_t)(q0 + qg * 16 + lr) * DHEAD + ks * 32 + lq * 8);

    // per-lane mask row pointers (row fixed for whole kernel)
    const unsigned long long* mrow0 = mb + (size_t)(q0 + lr) * (SEQL / 64);
    const unsigned long long* mrow1 = mb + (size_t)(q0 + 16 + lr) * (SEQL / 64);

    f32x4 o[4][2] = {};                      // O^T acc: [dgroup][qg]
    f32x4 lacc[2] = {};                      // row-sum acc via ones-MFMA

    const bf16 one = (bf16)1.0f;
    const bf16x8 ones8 = {one, one, one, one, one, one, one, one};

    // staging: lane sr reads K row sr / Vt row sr; K goes to permuted slot row
    const int sr = t >> 2, sc = (t & 3) * 16;
    const int zrow = ((sr >> 2) & 1) * 32 + ((sr >> 5) & 1) * 16 + ((sr >> 3) & 3) * 4 + (sr & 3);
    bf16x8 kreg[2], vreg[2];
    kreg[0] = *(const bf16x8*)(Kh  + (size_t)sr * DHEAD + sc);
    kreg[1] = *(const bf16x8*)(Kh  + (size_t)sr * DHEAD + sc + 8);
    vreg[0] = *(const bf16x8*)(Vth + (size_t)sr * SEQL + sc);
    vreg[1] = *(const bf16x8*)(Vth + (size_t)sr * SEQL + sc + 8);

    for (int kt = 0; kt < SEQL / 64; ++kt) {
        if (kt > 0) __syncthreads();         // readers of prev tile done
        *(bf16x8*)(Ksm  + zrow * 72 + sc)     = kreg[0];
        *(bf16x8*)(Ksm  + zrow * 72 + sc + 8) = kreg[1];
        *(bf16x8*)(Vtsm + sr * 72 + sc)       = vreg[0];
        *(bf16x8*)(Vtsm + sr * 72 + sc + 8)   = vreg[1];
        if (kt < SEQL / 64 - 1) {            // prefetch next tile into regs
            const int kb2 = (kt + 1) * 64;
            kreg[0] = *(const bf16x8*)(Kh  + (size_t)(kb2 + sr) * DHEAD + sc);
            kreg[1] = *(const bf16x8*)(Kh  + (size_t)(kb2 + sr) * DHEAD + sc + 8);
            vreg[0] = *(const bf16x8*)(Vth + (size_t)sr * SEQL + kb2 + sc);
            vreg[1] = *(const bf16x8*)(Vth + (size_t)sr * SEQL + kb2 + sc + 8);
        }
        __syncthreads();

        // ---- S^T = K·Q^T (K pre-scaled; rows permuted so C-layout = B-frag)
        f32x4 s[4][2] = {};
        #pragma unroll
        for (int ks = 0; ks < 2; ++ks) {
            bf16x8 kf[4];
            #pragma unroll
            for (int jj = 0; jj < 4; ++jj)
                kf[jj] = *(const bf16x8*)(Ksm + (jj * 16 + lr) * 72 + ks * 32 + lq * 8);
            #pragma unroll
            for (int jj = 0; jj < 4; ++jj)
                #pragma unroll
                for (int qg = 0; qg < 2; ++qg)
                    s[jj][qg] = MFMA16(kf[jj], qf[qg][ks], s[jj][qg], 0, 0, 0);
        }

        // ---- fused select->exp2->pack: s -> pf directly (no p[][] array).
        // s[jj][qg][r] holds key = (jj&1)*32 + lq*8 + (jj>>1)*4 + r.
        bf16x8 pf[2][2];
        #pragma unroll
        for (int qg = 0; qg < 2; ++qg) {
            const unsigned long long wmk = (qg == 0 ? mrow0 : mrow1)[kt];
            const unsigned lo = (unsigned)(wmk >> (lq * 8));
            const unsigned hi = (unsigned)(wmk >> 32) >> (lq * 8);
            #pragma unroll
            for (int ks = 0; ks < 2; ++ks) {
                const unsigned na = (ks == 0 ? lo : hi) & 15u;          // jj = ks
                const unsigned nb = ((ks == 0 ? lo : hi) >> 4) & 15u;   // jj = 2+ks
                bf16x8 pv;
                #pragma unroll
                for (int r = 0; r < 4; ++r) {
                    pv[r]     = (bf16)exp2f(((na >> r) & 1u) ? NEGB : s[ks][qg][r]);
                    pv[4 + r] = (bf16)exp2f(((nb >> r) & 1u) ? NEGB : s[2 + ks][qg][r]);
                }
                pf[qg][ks] = pv;
            }
        }

        // ---- l += 1·P  and  O^T += V^T·P  (no barrier: P is in registers)
        #pragma unroll
        for (int ks = 0; ks < 2; ++ks) {
            #pragma unroll
            for (int qg = 0; qg < 2; ++qg)
                lacc[qg] = MFMA16(ones8, pf[qg][ks], lacc[qg], 0, 0, 0);
            #pragma unroll
            for (int dg = 0; dg < 4; ++dg) {
                bf16x8 vf = *(const bf16x8*)(Vtsm + (dg * 16 + lr) * 72 + ks * 32 + lq * 8);
                #pragma unroll
                for (int qg = 0; qg < 2; ++qg)
                    o[dg][qg] = MFMA16(vf, pf[qg][ks], o[dg][qg], 0, 0, 0);
            }
        }
    }

    // ---- epilogue: vec[b][s][h*64+d]; lane qrow=lr, d=dg*16+lq*4+r -> b64 stores
    #pragma unroll
    for (int qg = 0; qg < 2; ++qg) {
        const float rl = 1.0f / lacc[qg][0];
        const size_t rowb = ((size_t)b * SEQL + q0 + qg * 16 + lr) * DM + h * DHEAD;
        #pragma unroll
        for (int dg = 0; dg < 4; ++dg) {
            bf16x4 ov;
            #pragma unroll
            for (int r = 0; r < 4; ++r) ov[r] = (bf16)(o[dg][qg][r] * rl);
            *(bf16x4*)(vec + rowb + dg * 16 + lq * 4) = ov;
        }
    }
}

// ---------------------------------------------------------------------------
extern "C" void kernel_launch(void* const* d_in, const int* in_sizes, int n_in,
                              void* d_out, int out_size, void* d_ws, size_t ws_size,
                              hipStream_t stream)
{
    const float* qin   = (const float*)d_in[0];
    const void*  mask  = d_in[1];
    const float* Wq    = (const float*)d_in[2];
    const float* Wk    = (const float*)d_in[3];
    const float* Wv    = (const float*)d_in[4];
    const float* Wo    = (const float*)d_in[5];
    const float* gamma = (const float*)d_in[6];
    const float* beta  = (const float*)d_in[7];
    float* out = (float*)d_out;

    char* w = (char*)d_ws;
    int*  flag = (int*)w;
    bf16* qnb  = (bf16*)(w + 256);                 // 8192x1024 bf16  (16 MB)
    bf16* Wt   = qnb + (size_t)8192 * 1024;        // 4x 1024x1024 bf16 (8 MB)
    bf16* Qb   = Wt + (size_t)4 * 1024 * 1024;     // (b,h,s,d)  (16 MB)
    bf16* Kb   = Qb + (size_t)8192 * 1024;         // (b,h,s,d)  (16 MB)
    bf16* Vtb  = Kb + (size_t)8192 * 1024;         // (b,h,d,s)  (16 MB)
    bf16* vec  = Vtb + (size_t)8192 * 1024;        // (b,s,h*d)  (16 MB)
    unsigned long long* mb = (unsigned long long*)(vec + (size_t)8192 * 1024); // 512 KB

    detect_mask<<<1, 256, 0, stream>>>((const unsigned int*)mask, flag);
    prep_bits<<<SEQL * (SEQL / 64) / 4, 256, 0, stream>>>(mask, flag, mb);
    ln_kernel<<<8192, 256, 0, stream>>>(qin, gamma, beta, qnb);
    cvt_w<<<dim3(32, 32, 4), dim3(32, 8), 0, stream>>>(Wq, Wk, Wv, Wo, Wt);
    qkv128<<<dim3(64, 24), 256, 0, stream>>>(qnb, Wt, Qb, Kb, Vtb);
    flash_attn<<<1024, 256, 0, stream>>>(Qb, Kb, Vtb, mb, vec);
    out128<<<dim3(64, 8), 256, 0, stream>>>(vec, Wt + (size_t)3 * 1024 * 1024, qnb, out);
}